// Round 6
// baseline (674.572 us; speedup 1.0000x reference)
//
#include <hip/hip_runtime.h>

typedef unsigned short u16;
typedef __attribute__((ext_vector_type(8))) short short8;
typedef __attribute__((ext_vector_type(16))) float f32x16;
typedef __attribute__((ext_vector_type(4))) u16 ushort4v;
typedef __attribute__((ext_vector_type(8))) u16 ushort8v;

#define DIM 2048
#define HID 5632
#define F2  11264
#define TTOT 8192

#define GLD(g, l) __builtin_amdgcn_global_load_lds(                       \
    (const __attribute__((address_space(1))) void*)(g),                   \
    (__attribute__((address_space(3))) void*)(l), 16, 0, 0)

__device__ __forceinline__ u16 f2bf(float f) {
  unsigned int u = __builtin_bit_cast(unsigned int, f);
  u += 0x7FFFu + ((u >> 16) & 1u);   // round-to-nearest-even (finite values)
  return (u16)(u >> 16);
}

// ---- weight conversion: w13 fp32 -> bf16, rows PERMUTED in 32/32 blocks:
// new row r: b=r>>6, i=r&63; orig = i<32 ? b*32+i : HID + b*32 + (i-32)
// -> per-wave n-block0 holds w1 rows, n-block1 the matching w3 rows (in-lane gate).
__global__ __launch_bounds__(256) void conv_w13(const float* __restrict__ w,
                                                u16* __restrict__ o) {
  int idx = blockIdx.x * 256 + threadIdx.x;          // 0 .. F2*DIM/4-1
  int rnew = idx >> 9;                               // DIM/4 = 512 float4/row
  int dc = (idx & 511) << 2;
  int b = rnew >> 6, ii = rnew & 63;
  int orig = (ii < 32) ? (b * 32 + ii) : (HID + b * 32 + (ii - 32));
  float4 v = *reinterpret_cast<const float4*>(w + (size_t)orig * DIM + dc);
  ushort4v q = {f2bf(v.x), f2bf(v.y), f2bf(v.z), f2bf(v.w)};
  *reinterpret_cast<ushort4v*>(o + (size_t)rnew * DIM + dc) = q;
}

__global__ __launch_bounds__(256) void conv_w2(const float* __restrict__ w,
                                               u16* __restrict__ o) {
  size_t e = ((size_t)blockIdx.x * 256 + threadIdx.x) * 4;
  float4 v = *reinterpret_cast<const float4*>(w + e);
  ushort4v q = {f2bf(v.x), f2bf(v.y), f2bf(v.z), f2bf(v.w)};
  *reinterpret_cast<ushort4v*>(o + e) = q;
}

// ---- per-token quant of x: q = rint(x*s) as bf16 (exact ints), scale = max/127
__global__ __launch_bounds__(256) void quant_x(const float* __restrict__ x,
                                               u16* __restrict__ q,
                                               float* __restrict__ scale) {
  const int t = blockIdx.x;
  const float* xr = x + (size_t)t * DIM;
  const int tid = threadIdx.x;
  float4 a = *reinterpret_cast<const float4*>(xr + tid * 8);
  float4 b = *reinterpret_cast<const float4*>(xr + tid * 8 + 4);
  float v[8] = {a.x, a.y, a.z, a.w, b.x, b.y, b.z, b.w};
  float m = 0.f;
#pragma unroll
  for (int i = 0; i < 8; ++i) m = fmaxf(m, fabsf(v[i]));
#pragma unroll
  for (int off = 32; off; off >>= 1) m = fmaxf(m, __shfl_xor(m, off));
  __shared__ float red[4];
  if ((tid & 63) == 0) red[tid >> 6] = m;
  __syncthreads();
  m = fmaxf(fmaxf(red[0], red[1]), fmaxf(red[2], red[3]));
  m = fmaxf(m, 1e-5f);
  float s = 127.0f / m;
  if (tid == 0) scale[t] = m / 127.0f;
  ushort8v o;
#pragma unroll
  for (int i = 0; i < 8; ++i) {
    float r = fminf(fmaxf(rintf(v[i] * s), -128.f), 127.f);
    o[i] = f2bf(r);
  }
  *reinterpret_cast<ushort8v*>(q + (size_t)t * DIM + tid * 8) = o;
}

// ---- gated row -> rmsnorm -> quant (bf16 ints) + scale
__global__ __launch_bounds__(256) void gate_nq(const float* __restrict__ G,
                                               const float* __restrict__ nw,
                                               u16* __restrict__ q2,
                                               float* __restrict__ s2) {
  const int t = blockIdx.x;
  const float* gr = G + (size_t)t * HID;
  const int tid = threadIdx.x;
  float4 vv[6];
  float ss = 0.f, mx = 0.f;
#pragma unroll
  for (int k = 0; k < 6; ++k) {
    int i = tid + k * 256;
    if (i < 1408) {
      float4 v = *reinterpret_cast<const float4*>(gr + i * 4);
      float4 w4 = *reinterpret_cast<const float4*>(nw + i * 4);
      vv[k] = v;
      ss += v.x * v.x + v.y * v.y + v.z * v.z + v.w * v.w;
      mx = fmaxf(mx, fmaxf(fmaxf(fabsf(v.x * w4.x), fabsf(v.y * w4.y)),
                           fmaxf(fabsf(v.z * w4.z), fabsf(v.w * w4.w))));
    }
  }
#pragma unroll
  for (int off = 32; off; off >>= 1) {
    ss += __shfl_xor(ss, off);
    mx = fmaxf(mx, __shfl_xor(mx, off));
  }
  __shared__ float rs[4], rm[4];
  if ((tid & 63) == 0) { rs[tid >> 6] = ss; rm[tid >> 6] = mx; }
  __syncthreads();
  ss = rs[0] + rs[1] + rs[2] + rs[3];
  mx = fmaxf(fmaxf(rm[0], rm[1]), fmaxf(rm[2], rm[3]));
  float rinv = 1.0f / sqrtf(ss * (1.0f / 5632.0f) + 1e-5f);
  float mi = fmaxf(mx * rinv, 1e-5f);
  float s = 127.0f / mi;
  if (tid == 0) s2[t] = mi / 127.0f;
  float fs = rinv * s;
#pragma unroll
  for (int k = 0; k < 6; ++k) {
    int i = tid + k * 256;
    if (i < 1408) {
      float4 v = vv[k];
      float4 w4 = *reinterpret_cast<const float4*>(nw + i * 4);
      ushort4v o;
      o.x = f2bf(fminf(fmaxf(rintf(v.x * w4.x * fs), -128.f), 127.f));
      o.y = f2bf(fminf(fmaxf(rintf(v.y * w4.y * fs), -128.f), 127.f));
      o.z = f2bf(fminf(fmaxf(rintf(v.z * w4.z * fs), -128.f), 127.f));
      o.w = f2bf(fminf(fmaxf(rintf(v.w * w4.w * fs), -128.f), 127.f));
      *reinterpret_cast<ushort4v*>(q2 + (size_t)t * HID + i * 4) = o;
    }
  }
}

// ============================================================================
// 256x256 8-phase GEMM on v_mfma_f32_32x32x16_bf16 (round-4 skeleton: frag
// ds_reads issued BEFORE the phase barrier, consumed right after; NO one-phase-
// ahead register pipeline -- round 5 showed that regresses).
// C[M,N] = A[M,K](bf16) @ B[N,K]^T(bf16), fp32 accum.
// 512 thr = 8 waves (2M x 4N); per-wave 128x64 out = 4 mb x 2 nb blocks of
// 32x32, acc f32x16 each. BK=64 (2 kk-halves of 32).
// LDS 128KB: [db][A/B][kk][256 rows][32 u16]; row r's chunk slot = q^((r>>1)&3)
// (both-sides permutation; staging unchanged from round 4, 0 conflicts).
// 32x32 frag read: lane l -> row base+ (l&31), k-chunk ks*2+(l>>5), swizzled;
// derived bank coverage: each 8-row stripe covers all 8 bank-groups exactly
// twice -> uniform, conflict-free.
// A operand: lane l holds A[row=l&31][k=(l>>5)*8+e] (ext. of verified 16x16);
// C/D: col=lane&31, row=(reg&3)+8*(reg>>2)+4*(lane>>5)  [m74/m101 verified].
// Stage schedule + vmcnt(6) identical to round 4 (verified). K-loop unrolled
// x2 so the db/dbuf indices are compile-time.
// GATE=1: w13 permuted in 32/32 blocks -> nb0=w1, nb1=w3; in-lane gate;
// gated col = nt*128 + wn*32 + (lane&31); C is [M, N/2].
// ============================================================================
template <int GATE>
__global__ __launch_bounds__(512, 2) void gemm8(
    const u16* __restrict__ A, const u16* __restrict__ B,
    const float* __restrict__ rowscale, float* __restrict__ C,
    int N, int K, int Ntiles) {
  __shared__ __attribute__((aligned(16))) u16 lds[2][2][2][256 * 32];
  const int NT = K >> 6;
  const int nwg = gridDim.x;
  const int orig = blockIdx.x;
  const int qq = nwg >> 3, rr = nwg & 7, xcd = orig & 7, sidx = orig >> 3;
  const int wg = (xcd < rr ? xcd * (qq + 1) : rr * (qq + 1) + (xcd - rr) * qq) + sidx;
  const int mt = wg / Ntiles, nt = wg % Ntiles;

  const int tid = threadIdx.x;
  const int wid = tid >> 6, lane = tid & 63;
  const int wm = wid >> 2, wn = wid & 3;
  const int r31 = lane & 31, q2 = lane >> 5;
  const int p = (lane >> 1) & 3;                  // = ((row)>>1)&3 for any row = r31 + 32k
  const int offq0 = ((0 * 2 + q2) ^ p) << 3;      // swizzled chunk slot, ks=0 (u16 units)
  const int offq1 = ((1 * 2 + q2) ^ p) << 3;      // ks=1
  const int aBase = (wm * 128 + r31) * 32;
  const int bBase = (wn * 64 + r31) * 32;

  // staging: row = tid>>2 (4 lanes/row, 64-B contiguous global segments),
  // source chunk = (tid&3) ^ ((row>>1)&3)  [inverse of the slot permutation]
  const int sr = tid >> 2;
  const int scol = ((tid & 3) ^ ((tid >> 3) & 3)) << 3;
  const u16* Ar = A + ((size_t)mt * 256 + sr) * K + scol;
  const u16* Br = B + ((size_t)nt * 256 + sr) * K + scol;
  const size_t rstep = (size_t)128 * K;

  f32x16 acc[4][2];
#pragma unroll
  for (int mb = 0; mb < 4; ++mb)
#pragma unroll
    for (int nb = 0; nb < 2; ++nb)
#pragma unroll
      for (int e = 0; e < 16; ++e) acc[mb][nb][e] = 0.f;

  auto stage = [&](int mat, int kk, int t, int buf) {
    if (t < NT) {
      const u16* g = (mat ? Br : Ar) + t * 64 + kk * 32;
      u16* l = &lds[buf][mat][kk][wid << 9];
      GLD(g, l);
      GLD(g + rstep, l + 4096);
    }
  };

#define LDA32(DB, KK, MH, AF)                                                 \
  {                                                                           \
    const u16* pa = &lds[DB][0][KK][0] + aBase + (MH) * 2048;                 \
    AF[0] = *reinterpret_cast<const short8*>(pa + offq0);                     \
    AF[1] = *reinterpret_cast<const short8*>(pa + offq1);                     \
    AF[2] = *reinterpret_cast<const short8*>(pa + 1024 + offq0);              \
    AF[3] = *reinterpret_cast<const short8*>(pa + 1024 + offq1);              \
  }
#define LDB32(DB, KK, BF)                                                     \
  {                                                                           \
    const u16* pb = &lds[DB][1][KK][0] + bBase;                               \
    BF[0] = *reinterpret_cast<const short8*>(pb + offq0);                     \
    BF[1] = *reinterpret_cast<const short8*>(pb + offq1);                     \
    BF[2] = *reinterpret_cast<const short8*>(pb + 1024 + offq0);              \
    BF[3] = *reinterpret_cast<const short8*>(pb + 1024 + offq1);              \
  }
// frag index: [mb2*2 + ks] for A, [nb*2 + ks] for B
#define MFMA8(AF, BF, MBOFS)                                                  \
  __builtin_amdgcn_s_setprio(1);                                              \
  _Pragma("unroll") for (int ks = 0; ks < 2; ++ks)                            \
      _Pragma("unroll") for (int mb2 = 0; mb2 < 2; ++mb2)                     \
          _Pragma("unroll") for (int nb = 0; nb < 2; ++nb)                    \
              acc[(MBOFS) + mb2][nb] = __builtin_amdgcn_mfma_f32_32x32x16_bf16( \
                  AF[mb2 * 2 + ks], BF[nb * 2 + ks], acc[(MBOFS) + mb2][nb],  \
                  0, 0, 0);                                                   \
  __builtin_amdgcn_s_setprio(0);                                              \
  __builtin_amdgcn_sched_barrier(0);
#define BARR asm volatile("s_barrier" ::: "memory")

#define KTILE(DB, U)                                                          \
  {                                                                           \
    short8 af[4], bfr[4];                                                     \
    /* ph1: MFMA(mh0,kk0) */                                                  \
    LDB32(DB, 0, bfr);                                                        \
    LDA32(DB, 0, 0, af);                                                      \
    stage(0, 1, (U) + 1, DB ^ 1);                                             \
    BARR;                                                                     \
    MFMA8(af, bfr, 0)                                                         \
    BARR;                                                                     \
    /* ph2: MFMA(mh1,kk0) */                                                  \
    LDA32(DB, 0, 1, af);                                                      \
    stage(1, 0, (U) + 2, DB);                                                 \
    BARR;                                                                     \
    MFMA8(af, bfr, 2)                                                         \
    BARR;                                                                     \
    /* ph3: MFMA(mh0,kk1) */                                                  \
    LDB32(DB, 1, bfr);                                                        \
    LDA32(DB, 1, 0, af);                                                      \
    stage(0, 0, (U) + 2, DB);                                                 \
    BARR;                                                                     \
    MFMA8(af, bfr, 0)                                                         \
    BARR;                                                                     \
    /* ph4: MFMA(mh1,kk1) */                                                  \
    LDA32(DB, 1, 1, af);                                                      \
    stage(1, 1, (U) + 2, DB);                                                 \
    if ((U) + 2 < NT) asm volatile("s_waitcnt vmcnt(6)" ::: "memory");        \
    else              asm volatile("s_waitcnt vmcnt(0)" ::: "memory");        \
    BARR;                                                                     \
    MFMA8(af, bfr, 2)                                                         \
    BARR;                                                                     \
  }

  // prologue: 7 halves (A-kk1[1] staged at ph1 of u=0); stream B0,A0,B1,A1
  stage(1, 0, 0, 0); stage(0, 0, 0, 0); stage(1, 1, 0, 0); stage(0, 1, 0, 0);
  stage(1, 0, 1, 1); stage(0, 0, 1, 1); stage(1, 1, 1, 1);
  asm volatile("s_waitcnt vmcnt(6)" ::: "memory");
  BARR;

  for (int u = 0; u < NT; u += 2) {   // NT even (K multiple of 128)
    KTILE(0, u)
    KTILE(1, u + 1)
  }

  // ---- epilogue. C/D: col = lane&31, row = (reg&3) + 8*(reg>>2) + 4*q2
  const int mbase0 = mt * 256 + wm * 128;
  if constexpr (GATE == 0) {
#pragma unroll
    for (int mb = 0; mb < 4; ++mb) {
#pragma unroll
      for (int reg = 0; reg < 16; ++reg) {
        const int row = mbase0 + mb * 32 + (reg & 3) + 8 * (reg >> 2) + 4 * q2;
        const float sc = rowscale[row];
        float* crow = C + (size_t)row * N + nt * 256 + wn * 64 + r31;
        crow[0]  = acc[mb][0][reg] * sc;
        crow[32] = acc[mb][1][reg] * sc;
      }
    }
  } else {
    const int H = N >> 1;
    const int gcol = nt * 128 + wn * 32 + r31;
#pragma unroll
    for (int mb = 0; mb < 4; ++mb) {
#pragma unroll
      for (int reg = 0; reg < 16; ++reg) {
        const int row = mbase0 + mb * 32 + (reg & 3) + 8 * (reg >> 2) + 4 * q2;
        const float sc = rowscale[row];
        const float s3 = sc * sc * sc;
        float a1 = acc[mb][0][reg];
        float a3 = acc[mb][1][reg];
        float rl = fmaxf(a1, 0.f);
        C[(size_t)row * H + gcol] = rl * rl * a3 * s3;
      }
    }
  }
}

extern "C" void kernel_launch(void* const* d_in, const int* in_sizes, int n_in,
                              void* d_out, int out_size, void* d_ws, size_t ws_size,
                              hipStream_t stream) {
  const float* x = (const float*)d_in[0];
  const float* w13 = (const float*)d_in[1];
  const float* w2 = (const float*)d_in[2];
  const float* nw = (const float*)d_in[3];
  float* out = (float*)d_out;

  char* p = (char*)d_ws;
  u16* w13p = (u16*)p; p += (size_t)F2 * DIM * 2;
  u16* w2b = (u16*)p;  p += (size_t)DIM * HID * 2;
  u16* q2f = (u16*)p;  p += (size_t)TTOT * HID * 2;
  float* s2f = (float*)p; p += (size_t)TTOT * 4;
  const size_t fixed = (size_t)F2 * DIM * 2 + (size_t)DIM * HID * 2 +
                       (size_t)TTOT * HID * 2 + (size_t)TTOT * 4;
  const size_t perTok = (size_t)DIM * 2 + (size_t)HID * 4 + 8;
  int Tc = TTOT;
  while (Tc > 256 && fixed + (size_t)Tc * perTok > ws_size) Tc >>= 1;
  u16* q1 = (u16*)p;        p += (size_t)Tc * DIM * 2;
  float* gated = (float*)p; p += (size_t)Tc * HID * 4;
  float* s1 = (float*)p;

  conv_w13<<<F2 * DIM / 4 / 256, 256, 0, stream>>>(w13, w13p);
  conv_w2<<<DIM * HID / 4 / 256, 256, 0, stream>>>(w2, w2b);

  for (int t0 = 0; t0 < TTOT; t0 += Tc) {
    quant_x<<<Tc, 256, 0, stream>>>(x + (size_t)t0 * DIM, q1, s1);
    gemm8<1><<<(Tc / 256) * (F2 / 256), 512, 0, stream>>>(q1, w13p, s1, gated,
                                                          F2, DIM, F2 / 256);
    gate_nq<<<Tc, 256, 0, stream>>>(gated, nw, q2f + (size_t)t0 * HID, s2f + t0);
  }
  gemm8<0><<<(TTOT / 256) * (DIM / 256), 512, 0, stream>>>(q2f, w2b, s2f, out,
                                                           DIM, HID, DIM / 256);
}

// Round 7
// 608.791 us; speedup vs baseline: 1.1081x; 1.1081x over previous
//
#include <hip/hip_runtime.h>

typedef unsigned short u16;
typedef __attribute__((ext_vector_type(8))) short short8;
typedef __attribute__((ext_vector_type(4))) float f32x4;
typedef __attribute__((ext_vector_type(4))) u16 ushort4v;
typedef __attribute__((ext_vector_type(8))) u16 ushort8v;

#define DIM 2048
#define HID 5632
#define F2  11264
#define TTOT 8192

#define GLD(g, l) __builtin_amdgcn_global_load_lds(                       \
    (const __attribute__((address_space(1))) void*)(g),                   \
    (__attribute__((address_space(3))) void*)(l), 16, 0, 0)

__device__ __forceinline__ u16 f2bf(float f) {
  unsigned int u = __builtin_bit_cast(unsigned int, f);
  u += 0x7FFFu + ((u >> 16) & 1u);   // round-to-nearest-even (finite values)
  return (u16)(u >> 16);
}

// ---- weight conversion: w13 fp32 -> bf16, rows PERMUTED so (x1,x3) pairs are
// 16-col groups: new row r: b=r>>5, i=r&31; orig = i<16 ? b*16+i : HID+b*16+(i-16)
__global__ __launch_bounds__(256) void conv_w13(const float* __restrict__ w,
                                                u16* __restrict__ o) {
  int idx = blockIdx.x * 256 + threadIdx.x;          // 0 .. F2*DIM/4-1
  int rnew = idx >> 9;                               // DIM/4 = 512 float4/row
  int dc = (idx & 511) << 2;
  int b = rnew >> 5, ii = rnew & 31;
  int orig = (ii < 16) ? (b * 16 + ii) : (HID + b * 16 + (ii - 16));
  float4 v = *reinterpret_cast<const float4*>(w + (size_t)orig * DIM + dc);
  ushort4v q = {f2bf(v.x), f2bf(v.y), f2bf(v.z), f2bf(v.w)};
  *reinterpret_cast<ushort4v*>(o + (size_t)rnew * DIM + dc) = q;
}

__global__ __launch_bounds__(256) void conv_w2(const float* __restrict__ w,
                                               u16* __restrict__ o) {
  size_t e = ((size_t)blockIdx.x * 256 + threadIdx.x) * 4;
  float4 v = *reinterpret_cast<const float4*>(w + e);
  ushort4v q = {f2bf(v.x), f2bf(v.y), f2bf(v.z), f2bf(v.w)};
  *reinterpret_cast<ushort4v*>(o + e) = q;
}

// ---- per-token quant of x: q = rint(x*s) as bf16 (exact ints), scale = max/127
__global__ __launch_bounds__(256) void quant_x(const float* __restrict__ x,
                                               u16* __restrict__ q,
                                               float* __restrict__ scale) {
  const int t = blockIdx.x;
  const float* xr = x + (size_t)t * DIM;
  const int tid = threadIdx.x;
  float4 a = *reinterpret_cast<const float4*>(xr + tid * 8);
  float4 b = *reinterpret_cast<const float4*>(xr + tid * 8 + 4);
  float v[8] = {a.x, a.y, a.z, a.w, b.x, b.y, b.z, b.w};
  float m = 0.f;
#pragma unroll
  for (int i = 0; i < 8; ++i) m = fmaxf(m, fabsf(v[i]));
#pragma unroll
  for (int off = 32; off; off >>= 1) m = fmaxf(m, __shfl_xor(m, off));
  __shared__ float red[4];
  if ((tid & 63) == 0) red[tid >> 6] = m;
  __syncthreads();
  m = fmaxf(fmaxf(red[0], red[1]), fmaxf(red[2], red[3]));
  m = fmaxf(m, 1e-5f);
  float s = 127.0f / m;
  if (tid == 0) scale[t] = m / 127.0f;
  ushort8v o;
#pragma unroll
  for (int i = 0; i < 8; ++i) {
    float r = fminf(fmaxf(rintf(v[i] * s), -128.f), 127.f);
    o[i] = f2bf(r);
  }
  *reinterpret_cast<ushort8v*>(q + (size_t)t * DIM + tid * 8) = o;
}

// ---- gated row -> rmsnorm -> quant (bf16 ints) + scale
__global__ __launch_bounds__(256) void gate_nq(const float* __restrict__ G,
                                               const float* __restrict__ nw,
                                               u16* __restrict__ q2,
                                               float* __restrict__ s2) {
  const int t = blockIdx.x;
  const float* gr = G + (size_t)t * HID;
  const int tid = threadIdx.x;
  float4 vv[6];
  float ss = 0.f, mx = 0.f;
#pragma unroll
  for (int k = 0; k < 6; ++k) {
    int i = tid + k * 256;
    if (i < 1408) {
      float4 v = *reinterpret_cast<const float4*>(gr + i * 4);
      float4 w4 = *reinterpret_cast<const float4*>(nw + i * 4);
      vv[k] = v;
      ss += v.x * v.x + v.y * v.y + v.z * v.z + v.w * v.w;
      mx = fmaxf(mx, fmaxf(fmaxf(fabsf(v.x * w4.x), fabsf(v.y * w4.y)),
                           fmaxf(fabsf(v.z * w4.z), fabsf(v.w * w4.w))));
    }
  }
#pragma unroll
  for (int off = 32; off; off >>= 1) {
    ss += __shfl_xor(ss, off);
    mx = fmaxf(mx, __shfl_xor(mx, off));
  }
  __shared__ float rs[4], rm[4];
  if ((tid & 63) == 0) { rs[tid >> 6] = ss; rm[tid >> 6] = mx; }
  __syncthreads();
  ss = rs[0] + rs[1] + rs[2] + rs[3];
  mx = fmaxf(fmaxf(rm[0], rm[1]), fmaxf(rm[2], rm[3]));
  float rinv = 1.0f / sqrtf(ss * (1.0f / 5632.0f) + 1e-5f);
  float mi = fmaxf(mx * rinv, 1e-5f);
  float s = 127.0f / mi;
  if (tid == 0) s2[t] = mi / 127.0f;
  float fs = rinv * s;
#pragma unroll
  for (int k = 0; k < 6; ++k) {
    int i = tid + k * 256;
    if (i < 1408) {
      float4 v = vv[k];
      float4 w4 = *reinterpret_cast<const float4*>(nw + i * 4);
      ushort4v o;
      o.x = f2bf(fminf(fmaxf(rintf(v.x * w4.x * fs), -128.f), 127.f));
      o.y = f2bf(fminf(fmaxf(rintf(v.y * w4.y * fs), -128.f), 127.f));
      o.z = f2bf(fminf(fmaxf(rintf(v.z * w4.z * fs), -128.f), 127.f));
      o.w = f2bf(fminf(fmaxf(rintf(v.w * w4.w * fs), -128.f), 127.f));
      *reinterpret_cast<ushort4v*>(q2 + (size_t)t * HID + i * 4) = o;
    }
  }
}

// ============================================================================
// 256x256 GEMM, round-4 data path, HALF the barriers: each phase is now
// {ds_read frags; stage; MFMA; phase-end barrier} -- the pre-MFMA barrier is
// deleted. Correctness audit (phase-end barriers only):
//  * every stage() targets a region whose last ds_read completed under that
//    wave's compiler-inserted lgkmcnt(0) BEFORE the preceding phase-end
//    barrier, and the asm "memory" clobber pins stage after that barrier;
//  * tile-residency proof unchanged: at ph4 vmcnt(6) leaves only the 8 newest
//    GLDs (tile u+2's 3 halves + u+1's A-kk1 pair) outstanding -> everything
//    older (all of tile u+1) complete; per-wave guarantee + barrier = global.
// Without the lockstep barrier the 2 waves/SIMD skew half a phase: one wave's
// ds_read burst overlaps the other's MFMA burst (pipe mixing).
// C[M,N] = A[M,K](bf16) @ B[N,K]^T(bf16), fp32 accum. 512 thr = 8 waves
// (2M x 4N); per-wave 128x64 out; BK=64 (2 kk-halves of 32).
// LDS 128KB: [db][A/B][kk][256 rows][32 u16]; row r's chunk slot = q^((r>>1)&3)
// (both-sides permutation; round 4 measured SQ_LDS_BANK_CONFLICT = 0).
// GATE=1: gated epilogue over interleaved-w13 n-pairs, C is [M,N/2].
// ============================================================================
template <int GATE>
__global__ __launch_bounds__(512, 2) void gemm8(
    const u16* __restrict__ A, const u16* __restrict__ B,
    const float* __restrict__ rowscale, float* __restrict__ C,
    int N, int K, int Ntiles) {
  __shared__ __attribute__((aligned(16))) u16 lds[2][2][2][256 * 32];
  const int NT = K >> 6;
  const int nwg = gridDim.x;
  const int orig = blockIdx.x;
  const int qq = nwg >> 3, rr = nwg & 7, xcd = orig & 7, sidx = orig >> 3;
  const int wg = (xcd < rr ? xcd * (qq + 1) : rr * (qq + 1) + (xcd - rr) * qq) + sidx;
  const int mt = wg / Ntiles, nt = wg % Ntiles;

  const int tid = threadIdx.x;
  const int wid = tid >> 6, lane = tid & 63;
  const int wm = wid >> 2, wn = wid & 3;
  const int c16 = lane & 15, q4 = lane >> 4;
  const int rA_base = wm * 128 + c16;
  const int rB_base = wn * 64 + c16;
  const int caf = (q4 ^ ((lane >> 1) & 3)) << 3;  // chunk slot q4^((row>>1)&3), u16 units

  // staging: row = tid>>2 (4 lanes/row, 64-B contiguous global segments),
  // source chunk = (tid&3) ^ ((row>>1)&3)  [inverse of the slot permutation]
  const int sr = tid >> 2;
  const int scol = ((tid & 3) ^ ((tid >> 3) & 3)) << 3;
  const u16* Ar = A + ((size_t)mt * 256 + sr) * K + scol;
  const u16* Br = B + ((size_t)nt * 256 + sr) * K + scol;
  const size_t rstep = (size_t)128 * K;

  f32x4 acc[8][4];
#pragma unroll
  for (int m = 0; m < 8; ++m)
#pragma unroll
    for (int n = 0; n < 4; ++n) acc[m][n] = f32x4{0.f, 0.f, 0.f, 0.f};

  auto stage = [&](int mat, int kk, int t) {
    if (t < NT) {
      const u16* g = (mat ? Br : Ar) + t * 64 + kk * 32;
      u16* l = &lds[t & 1][mat][kk][wid << 9];
      GLD(g, l);
      GLD(g + rstep, l + 4096);
    }
  };
  auto ldA = [&](int db, int kk, int mh, short8* af) {
#pragma unroll
    for (int m = 0; m < 4; ++m)
      af[m] = *reinterpret_cast<const short8*>(
          &lds[db][0][kk][(rA_base + (mh * 4 + m) * 16) * 32 + caf]);
  };
  auto ldB = [&](int db, int kk, short8* bfr) {
#pragma unroll
    for (int n = 0; n < 4; ++n)
      bfr[n] = *reinterpret_cast<const short8*>(
          &lds[db][1][kk][(rB_base + n * 16) * 32 + caf]);
  };

#define MFMA16(AF, BF, OFS)                                                   \
  __builtin_amdgcn_s_setprio(1);                                              \
  _Pragma("unroll") for (int m = 0; m < 4; ++m)                               \
      _Pragma("unroll") for (int n = 0; n < 4; ++n)                           \
          acc[(OFS) + m][n] = __builtin_amdgcn_mfma_f32_16x16x32_bf16(        \
              AF[m], BF[n], acc[(OFS) + m][n], 0, 0, 0);                      \
  __builtin_amdgcn_s_setprio(0);                                              \
  __builtin_amdgcn_sched_barrier(0);
#define BARR asm volatile("s_barrier" ::: "memory")

  // prologue: 7 halves (A-kk1[1] staged at ph1 of u=0); stream B0,A0,B1,A1
  stage(1, 0, 0); stage(0, 0, 0); stage(1, 1, 0); stage(0, 1, 0);
  stage(1, 0, 1); stage(0, 0, 1); stage(1, 1, 1);
  asm volatile("s_waitcnt vmcnt(6)" ::: "memory");
  BARR;

  for (int u = 0; u < NT; ++u) {
    const int db = u & 1;
    short8 af[4], bfr[4];
    // ---- phase 1: MFMA(mh0,kk0); stage A-kk1[u+1]
    ldB(db, 0, bfr);
    ldA(db, 0, 0, af);
    stage(0, 1, u + 1);
    MFMA16(af, bfr, 0)
    BARR;
    // ---- phase 2: MFMA(mh1,kk0); stage B-kk0[u+2]
    ldA(db, 0, 1, af);
    stage(1, 0, u + 2);
    MFMA16(af, bfr, 4)
    BARR;
    // ---- phase 3: MFMA(mh0,kk1); stage A-kk0[u+2]
    ldB(db, 1, bfr);
    ldA(db, 1, 0, af);
    stage(0, 0, u + 2);
    MFMA16(af, bfr, 0)
    BARR;
    // ---- phase 4: MFMA(mh1,kk1); stage B-kk1[u+2]; vmcnt AFTER compute
    ldA(db, 1, 1, af);
    stage(1, 1, u + 2);
    MFMA16(af, bfr, 4)
    if (u + 2 < NT) asm volatile("s_waitcnt vmcnt(6)" ::: "memory");
    else            asm volatile("s_waitcnt vmcnt(0)" ::: "memory");
    BARR;
  }

  // ---- epilogue
  const int mbase0 = mt * 256 + wm * 128;
  if constexpr (GATE == 0) {
#pragma unroll
    for (int m = 0; m < 8; ++m) {
#pragma unroll
      for (int j = 0; j < 4; ++j) {
        const int row = mbase0 + m * 16 + q4 * 4 + j;
        const float sc = rowscale[row];
        float* crow = C + (size_t)row * N + nt * 256 + wn * 64 + c16;
#pragma unroll
        for (int n = 0; n < 4; ++n) crow[n * 16] = acc[m][n][j] * sc;
      }
    }
  } else {
    const int H = N >> 1;
    const int gbase = (nt * 256 + wn * 64) >> 1;
#pragma unroll
    for (int m = 0; m < 8; ++m) {
#pragma unroll
      for (int j = 0; j < 4; ++j) {
        const int row = mbase0 + m * 16 + q4 * 4 + j;
        const float sc = rowscale[row];
        const float s3 = sc * sc * sc;
        float* grow = C + (size_t)row * H + gbase + c16;
#pragma unroll
        for (int p = 0; p < 2; ++p) {
          float a1 = acc[m][2 * p][j];
          float a3 = acc[m][2 * p + 1][j];
          float rl = fmaxf(a1, 0.f);
          grow[p * 16] = rl * rl * a3 * s3;
        }
      }
    }
  }
}

extern "C" void kernel_launch(void* const* d_in, const int* in_sizes, int n_in,
                              void* d_out, int out_size, void* d_ws, size_t ws_size,
                              hipStream_t stream) {
  const float* x = (const float*)d_in[0];
  const float* w13 = (const float*)d_in[1];
  const float* w2 = (const float*)d_in[2];
  const float* nw = (const float*)d_in[3];
  float* out = (float*)d_out;

  char* p = (char*)d_ws;
  u16* w13p = (u16*)p; p += (size_t)F2 * DIM * 2;
  u16* w2b = (u16*)p;  p += (size_t)DIM * HID * 2;
  u16* q2f = (u16*)p;  p += (size_t)TTOT * HID * 2;
  float* s2f = (float*)p; p += (size_t)TTOT * 4;
  const size_t fixed = (size_t)F2 * DIM * 2 + (size_t)DIM * HID * 2 +
                       (size_t)TTOT * HID * 2 + (size_t)TTOT * 4;
  const size_t perTok = (size_t)DIM * 2 + (size_t)HID * 4 + 8;
  int Tc = TTOT;
  while (Tc > 256 && fixed + (size_t)Tc * perTok > ws_size) Tc >>= 1;
  u16* q1 = (u16*)p;        p += (size_t)Tc * DIM * 2;
  float* gated = (float*)p; p += (size_t)Tc * HID * 4;
  float* s1 = (float*)p;

  conv_w13<<<F2 * DIM / 4 / 256, 256, 0, stream>>>(w13, w13p);
  conv_w2<<<DIM * HID / 4 / 256, 256, 0, stream>>>(w2, w2b);

  for (int t0 = 0; t0 < TTOT; t0 += Tc) {
    quant_x<<<Tc, 256, 0, stream>>>(x + (size_t)t0 * DIM, q1, s1);
    gemm8<1><<<(Tc / 256) * (F2 / 256), 512, 0, stream>>>(q1, w13p, s1, gated,
                                                          F2, DIM, F2 / 256);
    gate_nq<<<Tc, 256, 0, stream>>>(gated, nw, q2f + (size_t)t0 * HID, s2f + t0);
  }
  gemm8<0><<<(TTOT / 256) * (DIM / 256), 512, 0, stream>>>(q2f, w2b, s2f, out,
                                                           DIM, HID, DIM / 256);
}

// Round 8
// 597.589 us; speedup vs baseline: 1.1288x; 1.0187x over previous
//
#include <hip/hip_runtime.h>

typedef unsigned short u16;
typedef __attribute__((ext_vector_type(8))) short short8;
typedef __attribute__((ext_vector_type(4))) float f32x4;
typedef __attribute__((ext_vector_type(4))) u16 ushort4v;
typedef __attribute__((ext_vector_type(8))) u16 ushort8v;

#define DIM 2048
#define HID 5632
#define F2  11264
#define TTOT 8192

#define GLD(g, l) __builtin_amdgcn_global_load_lds(                       \
    (const __attribute__((address_space(1))) void*)(g),                   \
    (__attribute__((address_space(3))) void*)(l), 16, 0, 0)

__device__ __forceinline__ u16 f2bf(float f) {
  unsigned int u = __builtin_bit_cast(unsigned int, f);
  u += 0x7FFFu + ((u >> 16) & 1u);   // round-to-nearest-even (finite values)
  return (u16)(u >> 16);
}

// ---- weight conversion: w13 fp32 -> bf16, rows PERMUTED so (x1,x3) pairs are
// 16-col groups: new row r: b=r>>5, i=r&31; orig = i<16 ? b*16+i : HID+b*16+(i-16)
__global__ __launch_bounds__(256) void conv_w13(const float* __restrict__ w,
                                                u16* __restrict__ o) {
  int idx = blockIdx.x * 256 + threadIdx.x;          // 0 .. F2*DIM/4-1
  int rnew = idx >> 9;                               // DIM/4 = 512 float4/row
  int dc = (idx & 511) << 2;
  int b = rnew >> 5, ii = rnew & 31;
  int orig = (ii < 16) ? (b * 16 + ii) : (HID + b * 16 + (ii - 16));
  float4 v = *reinterpret_cast<const float4*>(w + (size_t)orig * DIM + dc);
  ushort4v q = {f2bf(v.x), f2bf(v.y), f2bf(v.z), f2bf(v.w)};
  *reinterpret_cast<ushort4v*>(o + (size_t)rnew * DIM + dc) = q;
}

__global__ __launch_bounds__(256) void conv_w2(const float* __restrict__ w,
                                               u16* __restrict__ o) {
  size_t e = ((size_t)blockIdx.x * 256 + threadIdx.x) * 4;
  float4 v = *reinterpret_cast<const float4*>(w + e);
  ushort4v q = {f2bf(v.x), f2bf(v.y), f2bf(v.z), f2bf(v.w)};
  *reinterpret_cast<ushort4v*>(o + e) = q;
}

// ---- per-token quant of x: q = rint(x*s) as bf16 (exact ints), scale = max/127
__global__ __launch_bounds__(256) void quant_x(const float* __restrict__ x,
                                               u16* __restrict__ q,
                                               float* __restrict__ scale) {
  const int t = blockIdx.x;
  const float* xr = x + (size_t)t * DIM;
  const int tid = threadIdx.x;
  float4 a = *reinterpret_cast<const float4*>(xr + tid * 8);
  float4 b = *reinterpret_cast<const float4*>(xr + tid * 8 + 4);
  float v[8] = {a.x, a.y, a.z, a.w, b.x, b.y, b.z, b.w};
  float m = 0.f;
#pragma unroll
  for (int i = 0; i < 8; ++i) m = fmaxf(m, fabsf(v[i]));
#pragma unroll
  for (int off = 32; off; off >>= 1) m = fmaxf(m, __shfl_xor(m, off));
  __shared__ float red[4];
  if ((tid & 63) == 0) red[tid >> 6] = m;
  __syncthreads();
  m = fmaxf(fmaxf(red[0], red[1]), fmaxf(red[2], red[3]));
  m = fmaxf(m, 1e-5f);
  float s = 127.0f / m;
  if (tid == 0) scale[t] = m / 127.0f;
  ushort8v o;
#pragma unroll
  for (int i = 0; i < 8; ++i) {
    float r = fminf(fmaxf(rintf(v[i] * s), -128.f), 127.f);
    o[i] = f2bf(r);
  }
  *reinterpret_cast<ushort8v*>(q + (size_t)t * DIM + tid * 8) = o;
}

// ---- gated row -> rmsnorm -> quant (bf16 ints) + scale
__global__ __launch_bounds__(256) void gate_nq(const float* __restrict__ G,
                                               const float* __restrict__ nw,
                                               u16* __restrict__ q2,
                                               float* __restrict__ s2) {
  const int t = blockIdx.x;
  const float* gr = G + (size_t)t * HID;
  const int tid = threadIdx.x;
  float4 vv[6];
  float ss = 0.f, mx = 0.f;
#pragma unroll
  for (int k = 0; k < 6; ++k) {
    int i = tid + k * 256;
    if (i < 1408) {
      float4 v = *reinterpret_cast<const float4*>(gr + i * 4);
      float4 w4 = *reinterpret_cast<const float4*>(nw + i * 4);
      vv[k] = v;
      ss += v.x * v.x + v.y * v.y + v.z * v.z + v.w * v.w;
      mx = fmaxf(mx, fmaxf(fmaxf(fabsf(v.x * w4.x), fabsf(v.y * w4.y)),
                           fmaxf(fabsf(v.z * w4.z), fabsf(v.w * w4.w))));
    }
  }
#pragma unroll
  for (int off = 32; off; off >>= 1) {
    ss += __shfl_xor(ss, off);
    mx = fmaxf(mx, __shfl_xor(mx, off));
  }
  __shared__ float rs[4], rm[4];
  if ((tid & 63) == 0) { rs[tid >> 6] = ss; rm[tid >> 6] = mx; }
  __syncthreads();
  ss = rs[0] + rs[1] + rs[2] + rs[3];
  mx = fmaxf(fmaxf(rm[0], rm[1]), fmaxf(rm[2], rm[3]));
  float rinv = 1.0f / sqrtf(ss * (1.0f / 5632.0f) + 1e-5f);
  float mi = fmaxf(mx * rinv, 1e-5f);
  float s = 127.0f / mi;
  if (tid == 0) s2[t] = mi / 127.0f;
  float fs = rinv * s;
#pragma unroll
  for (int k = 0; k < 6; ++k) {
    int i = tid + k * 256;
    if (i < 1408) {
      float4 v = vv[k];
      float4 w4 = *reinterpret_cast<const float4*>(nw + i * 4);
      ushort4v o;
      o.x = f2bf(fminf(fmaxf(rintf(v.x * w4.x * fs), -128.f), 127.f));
      o.y = f2bf(fminf(fmaxf(rintf(v.y * w4.y * fs), -128.f), 127.f));
      o.z = f2bf(fminf(fmaxf(rintf(v.z * w4.z * fs), -128.f), 127.f));
      o.w = f2bf(fminf(fmaxf(rintf(v.w * w4.w * fs), -128.f), 127.f));
      *reinterpret_cast<ushort4v*>(q2 + (size_t)t * HID + i * 4) = o;
    }
  }
}

// ============================================================================
// 256x256 GEMM, round-7 schedule (1 barrier/phase), ALL steady-state
// addressing compile-time: kernel templated on (N, K, Ntiles); K-loop
// unrolled x2 so the LDS double-buffer index is a LITERAL -> every
// ds_read/GLD-dest address is a loop-invariant base VGPR + immediate offset
// (hoisted once; zero per-phase VALU). Data path identical to round 7:
//  - LDS 128KB: [db][A/B][kk][256 rows][32 u16]; row r's chunk slot
//    = q ^ ((r>>1)&3) (both-sides permutation; measured 0 bank conflicts).
//  - phase = {ds_read frags; stage; MFMA; barrier}; vmcnt(6) once per K-tile
//    at ph4 (tile-residency proof unchanged); vmcnt(0) drain for last 2 tiles.
// C[M,N] = A[M,K](bf16) @ B[N,K]^T(bf16), fp32 accum. 512 thr = 8 waves
// (2M x 4N); per-wave 128x64 out; BK=64 (2 kk-halves of 32).
// GATE=1: gated epilogue over interleaved-w13 n-pairs, C is [M,N/2].
// ============================================================================
template <int GATE, int N, int K, int Ntiles>
__global__ __launch_bounds__(512, 2) void gemm8(
    const u16* __restrict__ A, const u16* __restrict__ B,
    const float* __restrict__ rowscale, float* __restrict__ C) {
  __shared__ __attribute__((aligned(16))) u16 lds[2][2][2][256 * 32];
  constexpr int NT = K >> 6;            // even for K=2048 (32) and K=5632 (88)
  const int nwg = gridDim.x;
  const int orig = blockIdx.x;
  const int qq = nwg >> 3, rr = nwg & 7, xcd = orig & 7, sidx = orig >> 3;
  const int wg = (xcd < rr ? xcd * (qq + 1) : rr * (qq + 1) + (xcd - rr) * qq) + sidx;
  const int mt = wg / Ntiles, nt = wg % Ntiles;

  const int tid = threadIdx.x;
  const int wid = tid >> 6, lane = tid & 63;
  const int wm = wid >> 2, wn = wid & 3;
  const int c16 = lane & 15, q4 = lane >> 4;
  const int rA_base = wm * 128 + c16;
  const int rB_base = wn * 64 + c16;
  const int caf = (q4 ^ ((lane >> 1) & 3)) << 3;  // chunk slot q4^((row>>1)&3), u16 units

  // staging: row = tid>>2 (4 lanes/row, 64-B contiguous global segments),
  // source chunk = (tid&3) ^ ((row>>1)&3)  [inverse of the slot permutation]
  const int sr = tid >> 2;
  const int scol = ((tid & 3) ^ ((tid >> 3) & 3)) << 3;
  const u16* Ar = A + ((size_t)mt * 256 + sr) * K + scol;
  const u16* Br = B + ((size_t)nt * 256 + sr) * K + scol;
  constexpr size_t rstep = (size_t)128 * K;

  f32x4 acc[8][4];
#pragma unroll
  for (int m = 0; m < 8; ++m)
#pragma unroll
    for (int n = 0; n < 4; ++n) acc[m][n] = f32x4{0.f, 0.f, 0.f, 0.f};

#define STAGE(MAT, KK, T, BUF)                                                \
  if ((T) < NT) {                                                             \
    const u16* g = ((MAT) ? Br : Ar) + (T) * 64 + (KK) * 32;                  \
    u16* l = &lds[BUF][MAT][KK][wid << 9];                                    \
    GLD(g, l);                                                                \
    GLD(g + rstep, l + 4096);                                                 \
  }
#define LDA(DB, KK, MH, AF)                                                   \
  _Pragma("unroll") for (int m = 0; m < 4; ++m)                               \
      AF[m] = *reinterpret_cast<const short8*>(                               \
          &lds[DB][0][KK][(rA_base + ((MH) * 4 + m) * 16) * 32 + caf]);
#define LDB(DB, KK, BF)                                                       \
  _Pragma("unroll") for (int n = 0; n < 4; ++n)                               \
      BF[n] = *reinterpret_cast<const short8*>(                               \
          &lds[DB][1][KK][(rB_base + n * 16) * 32 + caf]);
#define MFMA16(AF, BF, OFS)                                                   \
  __builtin_amdgcn_s_setprio(1);                                              \
  _Pragma("unroll") for (int m = 0; m < 4; ++m)                               \
      _Pragma("unroll") for (int n = 0; n < 4; ++n)                           \
          acc[(OFS) + m][n] = __builtin_amdgcn_mfma_f32_16x16x32_bf16(        \
              AF[m], BF[n], acc[(OFS) + m][n], 0, 0, 0);                      \
  __builtin_amdgcn_s_setprio(0);                                              \
  __builtin_amdgcn_sched_barrier(0);
#define BARR asm volatile("s_barrier" ::: "memory")

#define KTILE(DB, U)                                                          \
  {                                                                           \
    short8 af[4], bfr[4];                                                     \
    /* ph1: MFMA(mh0,kk0); stage A-kk1[U+1] */                                \
    LDB(DB, 0, bfr)                                                           \
    LDA(DB, 0, 0, af)                                                         \
    STAGE(0, 1, (U) + 1, DB ^ 1)                                              \
    MFMA16(af, bfr, 0)                                                        \
    BARR;                                                                     \
    /* ph2: MFMA(mh1,kk0); stage B-kk0[U+2] */                                \
    LDA(DB, 0, 1, af)                                                         \
    STAGE(1, 0, (U) + 2, DB)                                                  \
    MFMA16(af, bfr, 4)                                                        \
    BARR;                                                                     \
    /* ph3: MFMA(mh0,kk1); stage A-kk0[U+2] */                                \
    LDB(DB, 1, bfr)                                                           \
    LDA(DB, 1, 0, af)                                                         \
    STAGE(0, 0, (U) + 2, DB)                                                  \
    MFMA16(af, bfr, 0)                                                        \
    BARR;                                                                     \
    /* ph4: MFMA(mh1,kk1); stage B-kk1[U+2]; vmcnt AFTER compute */           \
    LDA(DB, 1, 1, af)                                                         \
    STAGE(1, 1, (U) + 2, DB)                                                  \
    MFMA16(af, bfr, 4)                                                        \
    if ((U) + 2 < NT) asm volatile("s_waitcnt vmcnt(6)" ::: "memory");        \
    else              asm volatile("s_waitcnt vmcnt(0)" ::: "memory");        \
    BARR;                                                                     \
  }

  // prologue: 7 halves (A-kk1[1] staged at ph1 of u=0); stream B0,A0,B1,A1
  STAGE(1, 0, 0, 0) STAGE(0, 0, 0, 0) STAGE(1, 1, 0, 0) STAGE(0, 1, 0, 0)
  STAGE(1, 0, 1, 1) STAGE(0, 0, 1, 1) STAGE(1, 1, 1, 1)
  asm volatile("s_waitcnt vmcnt(6)" ::: "memory");
  BARR;

#pragma unroll 1
  for (int u = 0; u < NT; u += 2) {
    KTILE(0, u)
    KTILE(1, u + 1)
  }

  // ---- epilogue
  const int mbase0 = mt * 256 + wm * 128;
  if constexpr (GATE == 0) {
#pragma unroll
    for (int m = 0; m < 8; ++m) {
#pragma unroll
      for (int j = 0; j < 4; ++j) {
        const int row = mbase0 + m * 16 + q4 * 4 + j;
        const float sc = rowscale[row];
        float* crow = C + (size_t)row * N + nt * 256 + wn * 64 + c16;
#pragma unroll
        for (int n = 0; n < 4; ++n) crow[n * 16] = acc[m][n][j] * sc;
      }
    }
  } else {
    constexpr int H = N >> 1;
    const int gbase = (nt * 256 + wn * 64) >> 1;
#pragma unroll
    for (int m = 0; m < 8; ++m) {
#pragma unroll
      for (int j = 0; j < 4; ++j) {
        const int row = mbase0 + m * 16 + q4 * 4 + j;
        const float sc = rowscale[row];
        const float s3 = sc * sc * sc;
        float* grow = C + (size_t)row * H + gbase + c16;
#pragma unroll
        for (int p = 0; p < 2; ++p) {
          float a1 = acc[m][2 * p][j];
          float a3 = acc[m][2 * p + 1][j];
          float rl = fmaxf(a1, 0.f);
          grow[p * 16] = rl * rl * a3 * s3;
        }
      }
    }
  }
}

extern "C" void kernel_launch(void* const* d_in, const int* in_sizes, int n_in,
                              void* d_out, int out_size, void* d_ws, size_t ws_size,
                              hipStream_t stream) {
  const float* x = (const float*)d_in[0];
  const float* w13 = (const float*)d_in[1];
  const float* w2 = (const float*)d_in[2];
  const float* nw = (const float*)d_in[3];
  float* out = (float*)d_out;

  char* p = (char*)d_ws;
  u16* w13p = (u16*)p; p += (size_t)F2 * DIM * 2;
  u16* w2b = (u16*)p;  p += (size_t)DIM * HID * 2;
  u16* q2f = (u16*)p;  p += (size_t)TTOT * HID * 2;
  float* s2f = (float*)p; p += (size_t)TTOT * 4;
  const size_t fixed = (size_t)F2 * DIM * 2 + (size_t)DIM * HID * 2 +
                       (size_t)TTOT * HID * 2 + (size_t)TTOT * 4;
  const size_t perTok = (size_t)DIM * 2 + (size_t)HID * 4 + 8;
  int Tc = TTOT;
  while (Tc > 256 && fixed + (size_t)Tc * perTok > ws_size) Tc >>= 1;
  u16* q1 = (u16*)p;        p += (size_t)Tc * DIM * 2;
  float* gated = (float*)p; p += (size_t)Tc * HID * 4;
  float* s1 = (float*)p;

  conv_w13<<<F2 * DIM / 4 / 256, 256, 0, stream>>>(w13, w13p);
  conv_w2<<<DIM * HID / 4 / 256, 256, 0, stream>>>(w2, w2b);

  for (int t0 = 0; t0 < TTOT; t0 += Tc) {
    quant_x<<<Tc, 256, 0, stream>>>(x + (size_t)t0 * DIM, q1, s1);
    gemm8<1, F2, DIM, F2 / 256><<<(Tc / 256) * (F2 / 256), 512, 0, stream>>>(
        q1, w13p, s1, gated);
    gate_nq<<<Tc, 256, 0, stream>>>(gated, nw, q2f + (size_t)t0 * HID, s2f + t0);
  }
  gemm8<0, DIM, HID, DIM / 256><<<(TTOT / 256) * (DIM / 256), 512, 0, stream>>>(
      q2f, w2b, s2f, out);
}